// Round 19
// baseline (102.558 us; speedup 1.0000x reference)
//
#include <hip/hip_runtime.h>

#define US unsigned short

typedef __bf16 bf16x8 __attribute__((ext_vector_type(8)));
typedef short s16x8 __attribute__((ext_vector_type(8)));
typedef short s16x4 __attribute__((ext_vector_type(4)));
typedef float f32x4 __attribute__((ext_vector_type(4)));
typedef unsigned u32x4 __attribute__((ext_vector_type(4)));

static __device__ __forceinline__ US f2bf(float f) {
  union { float f; unsigned u; } x; x.f = f;
  unsigned r = x.u + 0x7fffu + ((x.u >> 16) & 1u);
  return (US)(r >> 16);
}

// v_cvt_pk_bf16_f32: dst = bf16(lo) | bf16(hi)<<16, RNE (verified R8: bit-identical to f2bf)
static __device__ __forceinline__ unsigned cvtpk(float lo, float hi) {
  unsigned r;
  asm("v_cvt_pk_bf16_f32 %0, %1, %2" : "=v"(r) : "v"(lo), "v"(hi));
  return r;
}

static __device__ __forceinline__ void gload16(const US* g, US* l) {
  __builtin_amdgcn_global_load_lds(
      (const __attribute__((address_space(1))) void*)g,
      (__attribute__((address_space(3))) void*)l, 16, 0, 0);
}

// ---------------- prologue: transpose both weights (x-cast now fused into gemm1) ----------------
// blocks [0,1152): wqkT[n][r] = wqkv[r][n]*cexp(n<768), n<1536 (Q,K only; V dead)
// blocks [1152,1728): woutT[n][r] = wout[r][n]
__global__ __launch_bounds__(256) void prep(
    const float* __restrict__ wqkv, const float* __restrict__ wout,
    US* __restrict__ wqkT, US* __restrict__ woutT, float cexp) {
  __shared__ float t[32][33];
  const int bid = blockIdx.x, tid = threadIdx.x;
  const float* src;
  US* dst;
  int n0, r0, C, nlim;
  float scale;
  if (bid < 1152) {
    n0 = (bid % 48) * 32; r0 = (bid / 48) * 32;
    src = wqkv; dst = wqkT; C = 2304; nlim = 768; scale = cexp;
  } else {
    int tb = bid - 1152;
    n0 = (tb % 24) * 32; r0 = (tb / 24) * 32;
    src = wout; dst = woutT; C = 768; nlim = 0; scale = 1.0f;
  }
  const int R = 768;
  int tx = tid & 31, ty = tid >> 5;
  for (int i = 0; i < 4; ++i) {
    int r = i * 8 + ty;
    t[r][tx] = src[(size_t)(r0 + r) * C + n0 + tx];
  }
  __syncthreads();
  for (int i = 0; i < 4; ++i) {
    int n = i * 8 + ty;
    float s = (n0 + n < nlim) ? scale : 1.0f;
    dst[(size_t)(n0 + n) * R + r0 + tx] = f2bf(t[tx][n] * s);
  }
}

// ------- GEMM1: A = x (fp32, cast fused into staging), 128x128 2-phase, KT epilogue -------
// A-staging: reg-load 2xfloat4 -> cvtpk -> ds_write_b128 into the SAME swizzled
// LDS image as the old gload16 path (layout/bits unchanged). B via global_load_lds.
__global__ __launch_bounds__(256) void gemm1(
    const float* __restrict__ A, const US* __restrict__ Bt,
    US* __restrict__ Cv, US* __restrict__ KT) {
  const int K = 768, N = 1536;
  __shared__ US As[2][128 * 32];
  __shared__ US Bs[2][128 * 32];
  const int tid = threadIdx.x;
  const int wave = tid >> 6, lane = tid & 63;
  const int lr = lane & 15, lg = lane >> 4;
  const int m0 = blockIdx.x * 128, n0 = blockIdx.y * 128;
  const int wr = (wave >> 1) * 64, wc = (wave & 1) * 64;
  const int srow = tid >> 2;
  const int sseg = (tid & 3) ^ (srow & 3);
  const float* gA = A + (size_t)(m0 + srow) * K + sseg * 8;
  const US* gB = Bt + (size_t)(n0 + srow) * K + sseg * 8;

  f32x4 acc[4][4];
  for (int i = 0; i < 4; ++i)
    for (int j = 0; j < 4; ++j) acc[i][j] = (f32x4){0.f, 0.f, 0.f, 0.f};

  // load+cast one A half-row-pair into regs, write as b128 to the swizzled slot
  auto stageA = [&](int buf, int k0) {
#pragma unroll
    for (int i = 0; i < 2; ++i) {
      const float* p = gA + (size_t)i * 64 * K + k0;
      float4 va = *(const float4*)p;
      float4 vb = *(const float4*)(p + 4);
      u32x4 w;
      w[0] = cvtpk(va.x, va.y);
      w[1] = cvtpk(va.z, va.w);
      w[2] = cvtpk(vb.x, vb.y);
      w[3] = cvtpk(vb.z, vb.w);
      *(u32x4*)(&As[buf][tid * 8 + i * 2048]) = w;
    }
  };

  const int nIt = K >> 5;   // 24
  stageA(0, 0);
  for (int i = 0; i < 2; ++i)
    gload16(gB + (size_t)i * 64 * K, &Bs[0][tid * 8 + i * 2048]);
  __syncthreads();

  for (int it = 0; it < nIt; ++it) {
    if (it + 1 < nIt) {
      int k0 = (it + 1) * 32, bb = (it + 1) & 1;
      for (int i = 0; i < 2; ++i)
        gload16(gB + (size_t)i * 64 * K + k0, &Bs[bb][tid * 8 + i * 2048]);
      stageA(bb, k0);   // reg loads issue early; ds_write lands before barrier
    }
    const US* Ab = As[it & 1];
    const US* Bb = Bs[it & 1];
    bf16x8 af[4], bfr[4];
    for (int mi = 0; mi < 4; ++mi)
      af[mi] = *(const bf16x8*)(Ab + (wr + mi * 16 + lr) * 32 + ((lg ^ (lr & 3)) * 8));
    for (int ni = 0; ni < 4; ++ni)
      bfr[ni] = *(const bf16x8*)(Bb + (wc + ni * 16 + lr) * 32 + ((lg ^ (lr & 3)) * 8));
    for (int mi = 0; mi < 4; ++mi)
      for (int ni = 0; ni < 4; ++ni)
        acc[mi][ni] = __builtin_amdgcn_mfma_f32_16x16x32_bf16(
            af[mi], bfr[ni], acc[mi][ni], 0, 0, 0);
    __syncthreads();
  }

  for (int mi = 0; mi < 4; ++mi)
    for (int ni = 0; ni < 4; ++ni)
      for (int r = 0; r < 4; ++r) {
        size_t row = (size_t)m0 + wr + mi * 16 + lg * 4 + r;
        size_t col = (size_t)n0 + wc + ni * 16 + lr;
        Cv[row * N + col] = f2bf(acc[mi][ni][r]);
      }

  // Fused transposed-K emission (bit-identical to a separate transpose pass).
  if (n0 >= 768) {
    const int h = (n0 + wc - 768) >> 6;
    const int bb = m0 >> 10;
    const int sb = (m0 & 1023) + wr + lg * 4;
    US* ktp = KT + (size_t)(bb * 12 + h) * 64 * 1024;
    for (int mi = 0; mi < 4; ++mi)
      for (int ni = 0; ni < 4; ++ni) {
        int d = ni * 16 + lr;
        s16x4 w;
        w[0] = (short)f2bf(acc[mi][ni][0]);
        w[1] = (short)f2bf(acc[mi][ni][1]);
        w[2] = (short)f2bf(acc[mi][ni][2]);
        w[3] = (short)f2bf(acc[mi][ni][3]);
        *(s16x4*)(ktp + (size_t)d * 1024 + sb + mi * 16) = w;
      }
  }
}

// ---------------- GEMM2: 64x128 tile (grid-balanced: 768 blocks), fp32 out ----------------
__global__ __launch_bounds__(256) void gemm_bt2(
    const US* __restrict__ A, const US* __restrict__ Bt,
    float* __restrict__ Cv, int M, int N, int K) {
  __shared__ US As[2][64 * 32];
  __shared__ US Bs[2][128 * 32];
  const int tid = threadIdx.x;
  const int wave = tid >> 6, lane = tid & 63;
  const int lr = lane & 15, lg = lane >> 4;
  const int m0 = blockIdx.x * 64, n0 = blockIdx.y * 128;
  const int wr = (wave >> 1) * 32, wc = (wave & 1) * 64;
  const int srow = tid >> 2;
  const int sseg = (tid & 3) ^ (srow & 3);
  const US* gA = A + (size_t)(m0 + srow) * K + sseg * 8;
  const US* gB = Bt + (size_t)(n0 + srow) * K + sseg * 8;

  f32x4 acc[2][4];
  for (int i = 0; i < 2; ++i)
    for (int j = 0; j < 4; ++j) acc[i][j] = (f32x4){0.f, 0.f, 0.f, 0.f};

  const int nIt = K >> 5;
  gload16(gA, &As[0][tid * 8]);
  for (int i = 0; i < 2; ++i)
    gload16(gB + (size_t)i * 64 * K, &Bs[0][tid * 8 + i * 2048]);
  __syncthreads();

  for (int it = 0; it < nIt; ++it) {
    if (it + 1 < nIt) {
      int k0 = (it + 1) * 32, bb = (it + 1) & 1;
      gload16(gA + k0, &As[bb][tid * 8]);
      for (int i = 0; i < 2; ++i)
        gload16(gB + (size_t)i * 64 * K + k0, &Bs[bb][tid * 8 + i * 2048]);
    }
    const US* Ab = As[it & 1];
    const US* Bb = Bs[it & 1];
    bf16x8 af[2], bfr[4];
    for (int mi = 0; mi < 2; ++mi)
      af[mi] = *(const bf16x8*)(Ab + (wr + mi * 16 + lr) * 32 + ((lg ^ (lr & 3)) * 8));
    for (int ni = 0; ni < 4; ++ni)
      bfr[ni] = *(const bf16x8*)(Bb + (wc + ni * 16 + lr) * 32 + ((lg ^ (lr & 3)) * 8));
    for (int mi = 0; mi < 2; ++mi)
      for (int ni = 0; ni < 4; ++ni)
        acc[mi][ni] = __builtin_amdgcn_mfma_f32_16x16x32_bf16(
            af[mi], bfr[ni], acc[mi][ni], 0, 0, 0);
    __syncthreads();
  }

  for (int mi = 0; mi < 2; ++mi)
    for (int ni = 0; ni < 4; ++ni)
      for (int r = 0; r < 4; ++r) {
        size_t row = (size_t)m0 + wr + mi * 16 + lg * 4 + r;
        size_t col = (size_t)n0 + wc + ni * 16 + lr;
        Cv[row * N + col] = acc[mi][ni][r];
      }
}

// -------- per-fragment softmax + P routing (R6-proven routing, R8 cvtpk) --------
static __device__ __forceinline__ void softmax_route(
    const f32x4 sv[4], float& lsum, bool odd, bool hi, int laneQ0, int laneQ1,
    bf16x8& pa0v, bf16x8& pa1v) {
  float p[4][4];
#pragma unroll
  for (int ns = 0; ns < 4; ++ns)
#pragma unroll
    for (int r = 0; r < 4; ++r) {
      p[ns][r] = __builtin_amdgcn_exp2f(sv[ns][r]);
      lsum += p[ns][r];
    }
  unsigned pk00 = cvtpk(p[0][0], p[0][1]), pk01 = cvtpk(p[0][2], p[0][3]);
  unsigned pk10 = cvtpk(p[1][0], p[1][1]), pk11 = cvtpk(p[1][2], p[1][3]);
  unsigned pk20 = cvtpk(p[2][0], p[2][1]), pk21 = cvtpk(p[2][2], p[2][3]);
  unsigned pk30 = cvtpk(p[3][0], p[3][1]), pk31 = cvtpk(p[3][2], p[3][3]);
  int a0 = (int)(odd ? pk10 : pk00), a1 = (int)(odd ? pk11 : pk01);
  int a2 = (int)(odd ? pk30 : pk20), a3 = (int)(odd ? pk31 : pk21);
  int b0 = (int)(odd ? pk00 : pk10), b1 = (int)(odd ? pk01 : pk11);
  int b2 = (int)(odd ? pk20 : pk30), b3 = (int)(odd ? pk21 : pk31);
  int r0 = __shfl(a0, laneQ0), r1 = __shfl(a1, laneQ0);
  int r2 = __shfl(a2, laneQ0), r3 = __shfl(a3, laneQ0);
  int r4 = __shfl(b0, laneQ1), r5 = __shfl(b1, laneQ1);
  int r6 = __shfl(b2, laneQ1), r7 = __shfl(b3, laneQ1);
  union { unsigned u[4]; bf16x8 v; } pa0, pa1;
  pa0.u[0] = hi ? (unsigned)r4 : (unsigned)r0;
  pa0.u[1] = hi ? (unsigned)r5 : (unsigned)r1;
  pa0.u[2] = hi ? (unsigned)r0 : (unsigned)r4;
  pa0.u[3] = hi ? (unsigned)r1 : (unsigned)r5;
  pa1.u[0] = hi ? (unsigned)r6 : (unsigned)r2;
  pa1.u[1] = hi ? (unsigned)r7 : (unsigned)r3;
  pa1.u[2] = hi ? (unsigned)r2 : (unsigned)r6;
  pa1.u[3] = hi ? (unsigned)r3 : (unsigned)r7;
  pa0v = pa0.v;
  pa1v = pa1.v;
}

// ---------------- fused flash attention (K-as-V per reference, R8-verbatim) ----------------
__global__ __launch_bounds__(256, 3) void attn_kernel(
    const US* __restrict__ QK, const US* __restrict__ KTg, US* __restrict__ AO) {
  __shared__ US Kr[2][64 * 64];     // [kv][d], XOR-swz image
  __shared__ US Kt[2][64 * 64];     // [d][kv], XOR-swz image
  const int tid = threadIdx.x, wave = tid >> 6, lane = tid & 63;
  const int lr = lane & 15, lg = lane >> 4;
  const int id = blockIdx.y * 8 + blockIdx.x;
  const int bh = (id & 7) * 12 + ((id >> 3) % 12);
  const int qt = id / 96;
  const int b = bh / 12, h = bh % 12;
  const int qw = qt * 128 + wave * 32;
  const size_t rowbase = (size_t)b * 1024;
  const US* Qp = QK + rowbase * 1536 + h * 64;
  const US* Kp = QK + rowbase * 1536 + 768 + h * 64;
  const US* KTp = KTg + (size_t)bh * 64 * 1024;

  const int srow = tid >> 3;
  const int sseg = (tid & 7) ^ (srow & 7);
  const US* gK = Kp + (size_t)srow * 1536 + sseg * 8;
  const US* gT = KTp + (size_t)srow * 1024 + sseg * 8;

  bf16x8 qf0[2], qf1[2];
#pragma unroll
  for (int kk = 0; kk < 2; ++kk) {
    qf0[kk] = *(const bf16x8*)(Qp + (size_t)(qw + lr) * 1536 + kk * 32 + lg * 8);
    qf1[kk] = *(const bf16x8*)(Qp + (size_t)(qw + 16 + lr) * 1536 + kk * 32 + lg * 8);
  }

  const bool odd = (lg & 1) != 0;
  const bool hi = (lg >> 1) != 0;
  const int laneQ0 = lr + 32 * (lg & 1) + 16 * (lg >> 1);
  const int laneQ1 = lr + 32 * (lg & 1) + 16 * (1 - (lg >> 1));

  float lsum0 = 0.f, lsum1 = 0.f;
  f32x4 acc0[4], acc1[4];
#pragma unroll
  for (int d = 0; d < 4; ++d) {
    acc0[d] = (f32x4){0.f, 0.f, 0.f, 0.f};
    acc1[d] = (f32x4){0.f, 0.f, 0.f, 0.f};
  }

  for (int i = 0; i < 2; ++i) {
    gload16(gK + (size_t)(i * 32) * 1536, &Kr[0][tid * 8 + i * 2048]);
    gload16(gT + (size_t)(i * 32) * 1024, &Kt[0][tid * 8 + i * 2048]);
  }
  __syncthreads();

  for (int t = 0; t < 16; ++t) {
    if (t + 1 < 16) {
      int kv0 = (t + 1) * 64, bb = (t + 1) & 1;
      for (int i = 0; i < 2; ++i) {
        gload16(gK + (size_t)(kv0 + i * 32) * 1536, &Kr[bb][tid * 8 + i * 2048]);
        gload16(gT + (size_t)(i * 32) * 1024 + kv0, &Kt[bb][tid * 8 + i * 2048]);
      }
    }
    const US* Krb = Kr[t & 1];
    const US* Ktb = Kt[t & 1];

    f32x4 sv0[4], sv1[4];
    __builtin_amdgcn_s_setprio(1);
#pragma unroll
    for (int ns = 0; ns < 4; ++ns) {
      f32x4 a0 = {0.f, 0.f, 0.f, 0.f}, a1 = {0.f, 0.f, 0.f, 0.f};
#pragma unroll
      for (int kk = 0; kk < 2; ++kk) {
        bf16x8 kf = *(const bf16x8*)(
            Krb + (ns * 16 + lr) * 64 + (((kk * 4 + lg) ^ (lr & 7)) * 8));
        a0 = __builtin_amdgcn_mfma_f32_16x16x32_bf16(kf, qf0[kk], a0, 0, 0, 0);
        a1 = __builtin_amdgcn_mfma_f32_16x16x32_bf16(kf, qf1[kk], a1, 0, 0, 0);
      }
      sv0[ns] = a0; sv1[ns] = a1;
    }
    __builtin_amdgcn_s_setprio(0);

    bf16x8 pa00, pa01, pa10, pa11;
    softmax_route(sv0, lsum0, odd, hi, laneQ0, laneQ1, pa00, pa01);
    softmax_route(sv1, lsum1, odd, hi, laneQ0, laneQ1, pa10, pa11);

    __builtin_amdgcn_s_setprio(1);
#pragma unroll
    for (int d = 0; d < 4; ++d) {
      int drow = d * 16 + lr;
      bf16x8 kf0 = *(const bf16x8*)(Ktb + drow * 64 + ((lg ^ (lr & 7)) * 8));
      bf16x8 kf1 = *(const bf16x8*)(Ktb + drow * 64 + (((4 + lg) ^ (lr & 7)) * 8));
      acc0[d] = __builtin_amdgcn_mfma_f32_16x16x32_bf16(pa00, kf0, acc0[d], 0, 0, 0);
      acc0[d] = __builtin_amdgcn_mfma_f32_16x16x32_bf16(pa01, kf1, acc0[d], 0, 0, 0);
      acc1[d] = __builtin_amdgcn_mfma_f32_16x16x32_bf16(pa10, kf0, acc1[d], 0, 0, 0);
      acc1[d] = __builtin_amdgcn_mfma_f32_16x16x32_bf16(pa11, kf1, acc1[d], 0, 0, 0);
    }
    __builtin_amdgcn_s_setprio(0);
    __syncthreads();
  }

  lsum0 += __shfl_xor(lsum0, 16);
  lsum0 += __shfl_xor(lsum0, 32);
  lsum1 += __shfl_xor(lsum1, 16);
  lsum1 += __shfl_xor(lsum1, 32);
  float inv0[4], inv1[4];
#pragma unroll
  for (int r = 0; r < 4; ++r) {
    inv0[r] = 1.0f / __shfl(lsum0, lg * 4 + r);
    inv1[r] = 1.0f / __shfl(lsum1, lg * 4 + r);
  }
#pragma unroll
  for (int d = 0; d < 4; ++d)
#pragma unroll
    for (int r = 0; r < 4; ++r) {
      size_t row0 = rowbase + qw + lg * 4 + r;
      AO[row0 * 768 + h * 64 + d * 16 + lr] = f2bf(acc0[d][r] * inv0[r]);
      size_t row1 = rowbase + qw + 16 + lg * 4 + r;
      AO[row1 * 768 + h * 64 + d * 16 + lr] = f2bf(acc1[d][r] * inv1[r]);
    }
}

// ---------------- launch ----------------
extern "C" void kernel_launch(void* const* d_in, const int* in_sizes, int n_in,
                              void* d_out, int out_size, void* d_ws, size_t ws_size,
                              hipStream_t stream) {
  const float* x    = (const float*)d_in[0];   // [8,1024,768]
  const float* wqkv = (const float*)d_in[1];   // [768,2304]
  const float* wout = (const float*)d_in[2];   // [768,768]
  float* out = (float*)d_out;                  // [8,1024,768]

  US* wqkT  = (US*)d_ws;                        // [1536][768]   2.36 MB
  US* woutT = wqkT + (size_t)1536 * 768;        // [768][768]    1.18 MB
  US* QK    = woutT + (size_t)768 * 768;        // [8192][1536]  25.2 MB
  US* AO    = QK + (size_t)8192 * 1536;         // [8192][768]   12.6 MB
  US* KT    = AO + (size_t)8192 * 768;          // [96][64][1024] 12.6 MB
  // total ~54 MB (< previous 66.5 MB fused layout, which ran every round)

  const float cexp = 0.03608439182435161f * 1.4426950408889634f; // W^-0.5*log2e

  prep<<<1728, 256, 0, stream>>>(wqkv, wout, wqkT, woutT, cexp);
  gemm1<<<dim3(64, 12), 256, 0, stream>>>(x, wqkT, QK, KT);
  attn_kernel<<<dim3(8, 96), 256, 0, stream>>>(QK, KT, AO);
  gemm_bt2<<<dim3(128, 6), 256, 0, stream>>>(AO, woutT, out, 8192, 768, 768);
}

// Round 20
// 98.816 us; speedup vs baseline: 1.0379x; 1.0379x over previous
//
#include <hip/hip_runtime.h>

#define US unsigned short

typedef __bf16 bf16x8 __attribute__((ext_vector_type(8)));
typedef short s16x8 __attribute__((ext_vector_type(8)));
typedef short s16x4 __attribute__((ext_vector_type(4)));
typedef float f32x4 __attribute__((ext_vector_type(4)));

static __device__ __forceinline__ US f2bf(float f) {
  union { float f; unsigned u; } x; x.f = f;
  unsigned r = x.u + 0x7fffu + ((x.u >> 16) & 1u);
  return (US)(r >> 16);
}

// v_cvt_pk_bf16_f32: dst = bf16(lo) | bf16(hi)<<16, RNE (verified R8)
static __device__ __forceinline__ unsigned cvtpk(float lo, float hi) {
  unsigned r;
  asm("v_cvt_pk_bf16_f32 %0, %1, %2" : "=v"(r) : "v"(lo), "v"(hi));
  return r;
}

static __device__ __forceinline__ void gload16(const US* g, US* l) {
  __builtin_amdgcn_global_load_lds(
      (const __attribute__((address_space(1))) void*)g,
      (__attribute__((address_space(3))) void*)l, 16, 0, 0);
}

// ---------------- fused prologue: cast x + transpose both weights ----------------
__global__ __launch_bounds__(256) void prep(
    const float* __restrict__ x, const float* __restrict__ wqkv,
    const float* __restrict__ wout, US* __restrict__ xb,
    US* __restrict__ wqkT, US* __restrict__ woutT, float cexp) {
  __shared__ float t[32][33];
  const int bid = blockIdx.x, tid = threadIdx.x;
  if (bid < 3072) {
    int i = bid * 256 + tid;
    const float4* s = (const float4*)x + (size_t)i * 2;
    float4 a = s[0], b = s[1];
    s16x8 w;
    w[0] = (short)f2bf(a.x); w[1] = (short)f2bf(a.y);
    w[2] = (short)f2bf(a.z); w[3] = (short)f2bf(a.w);
    w[4] = (short)f2bf(b.x); w[5] = (short)f2bf(b.y);
    w[6] = (short)f2bf(b.z); w[7] = (short)f2bf(b.w);
    *(s16x8*)(xb + (size_t)i * 8) = w;
    return;
  }
  const float* src;
  US* dst;
  int n0, r0, C, nlim;
  float scale;
  if (bid < 4224) {
    int tb = bid - 3072;
    n0 = (tb % 48) * 32; r0 = (tb / 48) * 32;
    src = wqkv; dst = wqkT; C = 2304; nlim = 768; scale = cexp;
  } else {
    int tb = bid - 4224;
    n0 = (tb % 24) * 32; r0 = (tb / 24) * 32;
    src = wout; dst = woutT; C = 768; nlim = 0; scale = 1.0f;
  }
  const int R = 768;
  int tx = tid & 31, ty = tid >> 5;
  for (int i = 0; i < 4; ++i) {
    int r = i * 8 + ty;
    t[r][tx] = src[(size_t)(r0 + r) * C + n0 + tx];
  }
  __syncthreads();
  for (int i = 0; i < 4; ++i) {
    int n = i * 8 + ty;
    float s = (n0 + n < nlim) ? scale : 1.0f;
    dst[(size_t)(n0 + n) * R + r0 + tx] = f2bf(t[tx][n] * s);
  }
}

// ---------------- K transpose: KT[bh][d][s] (fallback path only) ----------------
__global__ __launch_bounds__(256) void kt_transpose(
    const US* __restrict__ QK, US* __restrict__ KT) {
  __shared__ US t[32][34];
  int bh = blockIdx.z, b = bh / 12, h = bh % 12;
  int s0 = blockIdx.x * 32, d0 = blockIdx.y * 32;
  int tx = threadIdx.x & 31, ty = threadIdx.x >> 5;
  const US* src = QK + ((size_t)b * 1024 + s0) * 1536 + 768 + h * 64 + d0;
  for (int i = 0; i < 4; ++i)
    t[i * 8 + ty][tx] = src[(size_t)(i * 8 + ty) * 1536 + tx];
  __syncthreads();
  US* dst = KT + ((size_t)bh * 64 + d0) * 1024 + s0;
  for (int i = 0; i < 4; ++i)
    dst[(size_t)(i * 8 + ty) * 1024 + tx] = t[tx][i * 8 + ty];
}

// ---------------- GEMM1: 128x128, 2-phase prefetch + fused KT epilogue ----------------
template<int FUSE_KT>
__global__ __launch_bounds__(256) void gemm_bt(
    const US* __restrict__ A, const US* __restrict__ Bt,
    US* __restrict__ Cv, int M, int N, int K, US* __restrict__ KT) {
  __shared__ US As[2][128 * 32];
  __shared__ US Bs[2][128 * 32];
  const int tid = threadIdx.x;
  const int wave = tid >> 6, lane = tid & 63;
  const int lr = lane & 15, lg = lane >> 4;
  const int m0 = blockIdx.x * 128, n0 = blockIdx.y * 128;
  const int wr = (wave >> 1) * 64, wc = (wave & 1) * 64;
  const int srow = tid >> 2;
  const int sseg = (tid & 3) ^ (srow & 3);
  const US* gA = A + (size_t)(m0 + srow) * K + sseg * 8;
  const US* gB = Bt + (size_t)(n0 + srow) * K + sseg * 8;

  f32x4 acc[4][4];
  for (int i = 0; i < 4; ++i)
    for (int j = 0; j < 4; ++j) acc[i][j] = (f32x4){0.f, 0.f, 0.f, 0.f};

  const int nIt = K >> 5;
  for (int i = 0; i < 2; ++i) {
    gload16(gA + (size_t)i * 64 * K, &As[0][tid * 8 + i * 2048]);
    gload16(gB + (size_t)i * 64 * K, &Bs[0][tid * 8 + i * 2048]);
  }
  __syncthreads();

  for (int it = 0; it < nIt; ++it) {
    if (it + 1 < nIt) {
      int k0 = (it + 1) * 32, bb = (it + 1) & 1;
      for (int i = 0; i < 2; ++i) {
        gload16(gA + (size_t)i * 64 * K + k0, &As[bb][tid * 8 + i * 2048]);
        gload16(gB + (size_t)i * 64 * K + k0, &Bs[bb][tid * 8 + i * 2048]);
      }
    }
    const US* Ab = As[it & 1];
    const US* Bb = Bs[it & 1];
    bf16x8 af[4], bfr[4];
    for (int mi = 0; mi < 4; ++mi)
      af[mi] = *(const bf16x8*)(Ab + (wr + mi * 16 + lr) * 32 + ((lg ^ (lr & 3)) * 8));
    for (int ni = 0; ni < 4; ++ni)
      bfr[ni] = *(const bf16x8*)(Bb + (wc + ni * 16 + lr) * 32 + ((lg ^ (lr & 3)) * 8));
    for (int mi = 0; mi < 4; ++mi)
      for (int ni = 0; ni < 4; ++ni)
        acc[mi][ni] = __builtin_amdgcn_mfma_f32_16x16x32_bf16(
            af[mi], bfr[ni], acc[mi][ni], 0, 0, 0);
    __syncthreads();
  }

  for (int mi = 0; mi < 4; ++mi)
    for (int ni = 0; ni < 4; ++ni)
      for (int r = 0; r < 4; ++r) {
        size_t row = (size_t)m0 + wr + mi * 16 + lg * 4 + r;
        size_t col = (size_t)n0 + wc + ni * 16 + lr;
        Cv[row * N + col] = f2bf(acc[mi][ni][r]);
      }

  if (FUSE_KT && n0 >= 768) {
    const int h = (n0 + wc - 768) >> 6;
    const int bb = m0 >> 10;
    const int sb = (m0 & 1023) + wr + lg * 4;
    US* ktp = KT + (size_t)(bb * 12 + h) * 64 * 1024;
    for (int mi = 0; mi < 4; ++mi)
      for (int ni = 0; ni < 4; ++ni) {
        int d = ni * 16 + lr;
        s16x4 w;
        w[0] = (short)f2bf(acc[mi][ni][0]);
        w[1] = (short)f2bf(acc[mi][ni][1]);
        w[2] = (short)f2bf(acc[mi][ni][2]);
        w[3] = (short)f2bf(acc[mi][ni][3]);
        *(s16x4*)(ktp + (size_t)d * 1024 + sb + mi * 16) = w;
      }
  }
}

// ---------------- GEMM2: 64x128 tile (grid-balanced: 768 blocks), fp32 out ----------------
__global__ __launch_bounds__(256) void gemm_bt2(
    const US* __restrict__ A, const US* __restrict__ Bt,
    float* __restrict__ Cv, int M, int N, int K) {
  __shared__ US As[2][64 * 32];
  __shared__ US Bs[2][128 * 32];
  const int tid = threadIdx.x;
  const int wave = tid >> 6, lane = tid & 63;
  const int lr = lane & 15, lg = lane >> 4;
  const int m0 = blockIdx.x * 64, n0 = blockIdx.y * 128;
  const int wr = (wave >> 1) * 32, wc = (wave & 1) * 64;
  const int srow = tid >> 2;
  const int sseg = (tid & 3) ^ (srow & 3);
  const US* gA = A + (size_t)(m0 + srow) * K + sseg * 8;
  const US* gB = Bt + (size_t)(n0 + srow) * K + sseg * 8;

  f32x4 acc[2][4];
  for (int i = 0; i < 2; ++i)
    for (int j = 0; j < 4; ++j) acc[i][j] = (f32x4){0.f, 0.f, 0.f, 0.f};

  const int nIt = K >> 5;
  gload16(gA, &As[0][tid * 8]);
  for (int i = 0; i < 2; ++i)
    gload16(gB + (size_t)i * 64 * K, &Bs[0][tid * 8 + i * 2048]);
  __syncthreads();

  for (int it = 0; it < nIt; ++it) {
    if (it + 1 < nIt) {
      int k0 = (it + 1) * 32, bb = (it + 1) & 1;
      gload16(gA + k0, &As[bb][tid * 8]);
      for (int i = 0; i < 2; ++i)
        gload16(gB + (size_t)i * 64 * K + k0, &Bs[bb][tid * 8 + i * 2048]);
    }
    const US* Ab = As[it & 1];
    const US* Bb = Bs[it & 1];
    bf16x8 af[2], bfr[4];
    for (int mi = 0; mi < 2; ++mi)
      af[mi] = *(const bf16x8*)(Ab + (wr + mi * 16 + lr) * 32 + ((lg ^ (lr & 3)) * 8));
    for (int ni = 0; ni < 4; ++ni)
      bfr[ni] = *(const bf16x8*)(Bb + (wc + ni * 16 + lr) * 32 + ((lg ^ (lr & 3)) * 8));
    for (int mi = 0; mi < 2; ++mi)
      for (int ni = 0; ni < 4; ++ni)
        acc[mi][ni] = __builtin_amdgcn_mfma_f32_16x16x32_bf16(
            af[mi], bfr[ni], acc[mi][ni], 0, 0, 0);
    __syncthreads();
  }

  for (int mi = 0; mi < 2; ++mi)
    for (int ni = 0; ni < 4; ++ni)
      for (int r = 0; r < 4; ++r) {
        size_t row = (size_t)m0 + wr + mi * 16 + lg * 4 + r;
        size_t col = (size_t)n0 + wc + ni * 16 + lr;
        Cv[row * N + col] = acc[mi][ni][r];
      }
}

// -------- per-fragment softmax + P routing (R6-proven routing, R8 cvtpk) --------
static __device__ __forceinline__ void softmax_route(
    const f32x4 sv[4], float& lsum, bool odd, bool hi, int laneQ0, int laneQ1,
    bf16x8& pa0v, bf16x8& pa1v) {
  float p[4][4];
#pragma unroll
  for (int ns = 0; ns < 4; ++ns)
#pragma unroll
    for (int r = 0; r < 4; ++r) {
      p[ns][r] = __builtin_amdgcn_exp2f(sv[ns][r]);
      lsum += p[ns][r];
    }
  unsigned pk00 = cvtpk(p[0][0], p[0][1]), pk01 = cvtpk(p[0][2], p[0][3]);
  unsigned pk10 = cvtpk(p[1][0], p[1][1]), pk11 = cvtpk(p[1][2], p[1][3]);
  unsigned pk20 = cvtpk(p[2][0], p[2][1]), pk21 = cvtpk(p[2][2], p[2][3]);
  unsigned pk30 = cvtpk(p[3][0], p[3][1]), pk31 = cvtpk(p[3][2], p[3][3]);
  int a0 = (int)(odd ? pk10 : pk00), a1 = (int)(odd ? pk11 : pk01);
  int a2 = (int)(odd ? pk30 : pk20), a3 = (int)(odd ? pk31 : pk21);
  int b0 = (int)(odd ? pk00 : pk10), b1 = (int)(odd ? pk01 : pk11);
  int b2 = (int)(odd ? pk20 : pk30), b3 = (int)(odd ? pk21 : pk31);
  int r0 = __shfl(a0, laneQ0), r1 = __shfl(a1, laneQ0);
  int r2 = __shfl(a2, laneQ0), r3 = __shfl(a3, laneQ0);
  int r4 = __shfl(b0, laneQ1), r5 = __shfl(b1, laneQ1);
  int r6 = __shfl(b2, laneQ1), r7 = __shfl(b3, laneQ1);
  union { unsigned u[4]; bf16x8 v; } pa0, pa1;
  pa0.u[0] = hi ? (unsigned)r4 : (unsigned)r0;
  pa0.u[1] = hi ? (unsigned)r5 : (unsigned)r1;
  pa0.u[2] = hi ? (unsigned)r0 : (unsigned)r4;
  pa0.u[3] = hi ? (unsigned)r1 : (unsigned)r5;
  pa1.u[0] = hi ? (unsigned)r6 : (unsigned)r2;
  pa1.u[1] = hi ? (unsigned)r7 : (unsigned)r3;
  pa1.u[2] = hi ? (unsigned)r2 : (unsigned)r6;
  pa1.u[3] = hi ? (unsigned)r3 : (unsigned)r7;
  pa0v = pa0.v;
  pa1v = pa1.v;
}

// ---------------- fused flash attention (K-as-V per reference, R8-verbatim) ----------------
__global__ __launch_bounds__(256, 3) void attn_kernel(
    const US* __restrict__ QK, const US* __restrict__ KTg, US* __restrict__ AO) {
  __shared__ US Kr[2][64 * 64];     // [kv][d], XOR-swz image
  __shared__ US Kt[2][64 * 64];     // [d][kv], XOR-swz image
  const int tid = threadIdx.x, wave = tid >> 6, lane = tid & 63;
  const int lr = lane & 15, lg = lane >> 4;
  const int id = blockIdx.y * 8 + blockIdx.x;
  const int bh = (id & 7) * 12 + ((id >> 3) % 12);
  const int qt = id / 96;
  const int b = bh / 12, h = bh % 12;
  const int qw = qt * 128 + wave * 32;
  const size_t rowbase = (size_t)b * 1024;
  const US* Qp = QK + rowbase * 1536 + h * 64;
  const US* Kp = QK + rowbase * 1536 + 768 + h * 64;
  const US* KTp = KTg + (size_t)bh * 64 * 1024;

  const int srow = tid >> 3;
  const int sseg = (tid & 7) ^ (srow & 7);
  const US* gK = Kp + (size_t)srow * 1536 + sseg * 8;
  const US* gT = KTp + (size_t)srow * 1024 + sseg * 8;

  bf16x8 qf0[2], qf1[2];
#pragma unroll
  for (int kk = 0; kk < 2; ++kk) {
    qf0[kk] = *(const bf16x8*)(Qp + (size_t)(qw + lr) * 1536 + kk * 32 + lg * 8);
    qf1[kk] = *(const bf16x8*)(Qp + (size_t)(qw + 16 + lr) * 1536 + kk * 32 + lg * 8);
  }

  const bool odd = (lg & 1) != 0;
  const bool hi = (lg >> 1) != 0;
  const int laneQ0 = lr + 32 * (lg & 1) + 16 * (lg >> 1);
  const int laneQ1 = lr + 32 * (lg & 1) + 16 * (1 - (lg >> 1));

  float lsum0 = 0.f, lsum1 = 0.f;
  f32x4 acc0[4], acc1[4];
#pragma unroll
  for (int d = 0; d < 4; ++d) {
    acc0[d] = (f32x4){0.f, 0.f, 0.f, 0.f};
    acc1[d] = (f32x4){0.f, 0.f, 0.f, 0.f};
  }

  for (int i = 0; i < 2; ++i) {
    gload16(gK + (size_t)(i * 32) * 1536, &Kr[0][tid * 8 + i * 2048]);
    gload16(gT + (size_t)(i * 32) * 1024, &Kt[0][tid * 8 + i * 2048]);
  }
  __syncthreads();

  for (int t = 0; t < 16; ++t) {
    if (t + 1 < 16) {
      int kv0 = (t + 1) * 64, bb = (t + 1) & 1;
      for (int i = 0; i < 2; ++i) {
        gload16(gK + (size_t)(kv0 + i * 32) * 1536, &Kr[bb][tid * 8 + i * 2048]);
        gload16(gT + (size_t)(i * 32) * 1024 + kv0, &Kt[bb][tid * 8 + i * 2048]);
      }
    }
    const US* Krb = Kr[t & 1];
    const US* Ktb = Kt[t & 1];

    f32x4 sv0[4], sv1[4];
    __builtin_amdgcn_s_setprio(1);
#pragma unroll
    for (int ns = 0; ns < 4; ++ns) {
      f32x4 a0 = {0.f, 0.f, 0.f, 0.f}, a1 = {0.f, 0.f, 0.f, 0.f};
#pragma unroll
      for (int kk = 0; kk < 2; ++kk) {
        bf16x8 kf = *(const bf16x8*)(
            Krb + (ns * 16 + lr) * 64 + (((kk * 4 + lg) ^ (lr & 7)) * 8));
        a0 = __builtin_amdgcn_mfma_f32_16x16x32_bf16(kf, qf0[kk], a0, 0, 0, 0);
        a1 = __builtin_amdgcn_mfma_f32_16x16x32_bf16(kf, qf1[kk], a1, 0, 0, 0);
      }
      sv0[ns] = a0; sv1[ns] = a1;
    }
    __builtin_amdgcn_s_setprio(0);

    bf16x8 pa00, pa01, pa10, pa11;
    softmax_route(sv0, lsum0, odd, hi, laneQ0, laneQ1, pa00, pa01);
    softmax_route(sv1, lsum1, odd, hi, laneQ0, laneQ1, pa10, pa11);

    __builtin_amdgcn_s_setprio(1);
#pragma unroll
    for (int d = 0; d < 4; ++d) {
      int drow = d * 16 + lr;
      bf16x8 kf0 = *(const bf16x8*)(Ktb + drow * 64 + ((lg ^ (lr & 7)) * 8));
      bf16x8 kf1 = *(const bf16x8*)(Ktb + drow * 64 + (((4 + lg) ^ (lr & 7)) * 8));
      acc0[d] = __builtin_amdgcn_mfma_f32_16x16x32_bf16(pa00, kf0, acc0[d], 0, 0, 0);
      acc0[d] = __builtin_amdgcn_mfma_f32_16x16x32_bf16(pa01, kf1, acc0[d], 0, 0, 0);
      acc1[d] = __builtin_amdgcn_mfma_f32_16x16x32_bf16(pa10, kf0, acc1[d], 0, 0, 0);
      acc1[d] = __builtin_amdgcn_mfma_f32_16x16x32_bf16(pa11, kf1, acc1[d], 0, 0, 0);
    }
    __builtin_amdgcn_s_setprio(0);
    __syncthreads();
  }

  lsum0 += __shfl_xor(lsum0, 16);
  lsum0 += __shfl_xor(lsum0, 32);
  lsum1 += __shfl_xor(lsum1, 16);
  lsum1 += __shfl_xor(lsum1, 32);
  float inv0[4], inv1[4];
#pragma unroll
  for (int r = 0; r < 4; ++r) {
    inv0[r] = 1.0f / __shfl(lsum0, lg * 4 + r);
    inv1[r] = 1.0f / __shfl(lsum1, lg * 4 + r);
  }
#pragma unroll
  for (int d = 0; d < 4; ++d)
#pragma unroll
    for (int r = 0; r < 4; ++r) {
      size_t row0 = rowbase + qw + lg * 4 + r;
      AO[row0 * 768 + h * 64 + d * 16 + lr] = f2bf(acc0[d][r] * inv0[r]);
      size_t row1 = rowbase + qw + 16 + lg * 4 + r;
      AO[row1 * 768 + h * 64 + d * 16 + lr] = f2bf(acc1[d][r] * inv1[r]);
    }
}

// ---------------- launch ----------------
extern "C" void kernel_launch(void* const* d_in, const int* in_sizes, int n_in,
                              void* d_out, int out_size, void* d_ws, size_t ws_size,
                              hipStream_t stream) {
  const float* x    = (const float*)d_in[0];   // [8,1024,768]
  const float* wqkv = (const float*)d_in[1];   // [768,2304]
  const float* wout = (const float*)d_in[2];   // [768,768]
  float* out = (float*)d_out;                  // [8,1024,768]

  US* wqkT  = (US*)d_ws;                        // [1536][768]
  US* woutT = wqkT + (size_t)1536 * 768;        // [768][768]
  US* QK    = woutT + (size_t)768 * 768;        // [8192][1536]
  US* AO    = QK + (size_t)8192 * 1536;         // [8192][768]
  US* xb    = AO + (size_t)8192 * 768;          // [8192][768]
  const size_t needElems = (size_t)1536 * 768 + (size_t)768 * 768 +
                           (size_t)8192 * 1536 + (size_t)8192 * 768 * 2 +
                           (size_t)96 * 64 * 1024;
  const bool fuse = ws_size >= needElems * sizeof(US);
  US* KT = fuse ? (xb + (size_t)8192 * 768) : xb;  // fallback: alias dead xb

  const float cexp = 0.03608439182435161f * 1.4426950408889634f; // W^-0.5*log2e

  prep<<<4800, 256, 0, stream>>>(x, wqkv, wout, xb, wqkT, woutT, cexp);
  if (fuse) {
    gemm_bt<1><<<dim3(64, 12), 256, 0, stream>>>(xb, wqkT, QK, 8192, 1536, 768, KT);
  } else {
    gemm_bt<0><<<dim3(64, 12), 256, 0, stream>>>(xb, wqkT, QK, 8192, 1536, 768, nullptr);
    kt_transpose<<<dim3(32, 2, 96), 256, 0, stream>>>(QK, KT);
  }
  attn_kernel<<<dim3(8, 96), 256, 0, stream>>>(QK, KT, AO);
  gemm_bt2<<<dim3(128, 6), 256, 0, stream>>>(AO, woutT, out, 8192, 768, 768);
}